// Round 16
// baseline (743.306 us; speedup 1.0000x reference)
//
#include <hip/hip_runtime.h>
#include <hip/hip_bf16.h>

typedef __attribute__((ext_vector_type(8))) short bf16x8;
typedef __attribute__((ext_vector_type(4))) float f32x4;

__device__ __forceinline__ short f2b(float f) {
  return __builtin_bit_cast(short, __float2bfloat16(f));
}
__device__ __forceinline__ float b2f(short s) {
  unsigned u = ((unsigned)(unsigned short)s) << 16;
  return __builtin_bit_cast(float, u);
}

__device__ __forceinline__ void gload16(const void* g, void* l) {
  __builtin_amdgcn_global_load_lds(
      (const __attribute__((address_space(1))) void*)g,
      (__attribute__((address_space(3))) void*)l, 16, 0, 0);
}

// sigmoid-form GELU: v*sigmoid(1.702v)
__device__ __forceinline__ float gelu_f(float v) {
  float e = __builtin_amdgcn_exp2f(-2.45537082f * v);
  return v * __builtin_amdgcn_rcpf(1.f + e);
}

// ---------------- packing kernels ----------------
__global__ void cvt_bf16_vec(const float* __restrict__ src, short* __restrict__ dst, long n) {
  long i = ((long)blockIdx.x * 256 + threadIdx.x) * 8;
  if (i >= n) return;
  f32x4 a = *(const f32x4*)(src + i);
  f32x4 b = *(const f32x4*)(src + i + 4);
  bf16x8 o;
#pragma unroll
  for (int j = 0; j < 4; j++) o[j] = f2b(a[j]);
#pragma unroll
  for (int j = 0; j < 4; j++) o[j + 4] = f2b(b[j]);
  *(bf16x8*)(dst + i) = o;
}

// All 6 weight transposes + bias pack in ONE launch.
__global__ void pack_all(const float* __restrict__ wq, const float* __restrict__ wk,
                         const float* __restrict__ wv, const float* __restrict__ wo,
                         const float* __restrict__ wfc1, const float* __restrict__ wfc2,
                         const float* __restrict__ bq, const float* __restrict__ bk,
                         const float* __restrict__ bv,
                         short* __restrict__ WQKVT, short* __restrict__ WOT,
                         short* __restrict__ WFC1T, short* __restrict__ WFC2T,
                         float* __restrict__ BQKV) {
  const int b = blockIdx.x;
  if (b >= 3072) {  // bias block
    for (int t = threadIdx.x; t < 1536; t += 256)
      BQKV[t] = (t < 512) ? bq[t] : ((t < 1024) ? bk[t - 512] : bv[t - 1024]);
    return;
  }
  __shared__ float tile[32][33];
  const float* src;
  short* dst;
  int K, N, tb;
  if (b < 256)       { src = wq;   dst = WQKVT;              K = 512;  N = 512;  tb = b; }
  else if (b < 512)  { src = wk;   dst = WQKVT + 512 * 512;  K = 512;  N = 512;  tb = b - 256; }
  else if (b < 768)  { src = wv;   dst = WQKVT + 1024 * 512; K = 512;  N = 512;  tb = b - 512; }
  else if (b < 1024) { src = wo;   dst = WOT;                K = 512;  N = 512;  tb = b - 768; }
  else if (b < 2048) { src = wfc1; dst = WFC1T;              K = 512;  N = 2048; tb = b - 1024; }
  else               { src = wfc2; dst = WFC2T;              K = 2048; N = 512;  tb = b - 2048; }
  const int ntx = N >> 5;
  const int n0 = (tb % ntx) * 32, k0 = (tb / ntx) * 32;
  const int j = threadIdx.x & 31, i0 = threadIdx.x >> 5;
#pragma unroll
  for (int r = 0; r < 4; r++) {
    int i = i0 + r * 8;
    tile[i][j] = src[(long)(k0 + i) * N + n0 + j];
  }
  __syncthreads();
#pragma unroll
  for (int r = 0; r < 4; r++) {
    int i = i0 + r * 8;
    dst[(long)(n0 + i) * K + k0 + j] = f2b(tile[j][i]);
  }
}

// ======== 128x256 ring GEMM (fc1) — per-wave 64x128, BK=32, 3-buf ring =====
template <int EPI>  // 1: bf16 gelu(v+bias)
__global__ __launch_bounds__(256, 2) void gemm_bt2(
    const short* __restrict__ A, const short* __restrict__ Bt,
    const float* __restrict__ bias, void* __restrict__ Cout, int K, int ldc, int gxN) {
  __shared__ short lds[3 * 12288];
  const int t = threadIdx.x;
  const int w = t >> 6, lane = t & 63;
  const int lr = lane & 15, lg = lane >> 4;

  const int nwg = gridDim.x;
  const int orig = blockIdx.x;
  const int q = nwg >> 3, r = nwg & 7, xcd = orig & 7, idx = orig >> 3;
  const int swz = (xcd < r ? xcd * (q + 1) : r * (q + 1) + (xcd - r) * q) + idx;
  const long m0 = (long)(swz / gxN) * 128;
  const int n0 = (swz % gxN) * 256;

  const int wm = (w >> 1) * 64, wn = (w & 1) * 128;

  f32x4 acc[4][8];
#pragma unroll
  for (int i = 0; i < 4; i++)
#pragma unroll
    for (int j = 0; j < 8; j++) acc[i][j] = f32x4{0.f, 0.f, 0.f, 0.f};

  const int srow = t >> 2;
  const int schunk = (t & 3) ^ ((t >> 3) & 3);
  const short* Ag = A + (m0 + srow) * (long)K + schunk * 8;
  const short* Bg = Bt + ((long)n0 + srow) * K + schunk * 8;
  const long half = (long)64 * K;

#define STAGE(b, kt)                                       \
  {                                                        \
    short* d = lds + (b) * 12288 + t * 8;                  \
    gload16(Ag + (long)(kt) * 32, d);                      \
    gload16(Ag + half + (long)(kt) * 32, d + 2048);        \
    short* db = d + 4096;                                  \
    gload16(Bg + (long)(kt) * 32, db);                     \
    gload16(Bg + half + (long)(kt) * 32, db + 2048);       \
    gload16(Bg + 2 * half + (long)(kt) * 32, db + 4096);   \
    gload16(Bg + 3 * half + (long)(kt) * 32, db + 6144);   \
  }

  const int xsw = (lg ^ ((lr >> 1) & 3)) * 8;
  const int aoff = (wm + lr) * 32 + xsw;
  const int boff = 4096 + (wn + lr) * 32 + xsw;

#define TILE_WAIT(WN)                                        \
  asm volatile("s_waitcnt vmcnt(" #WN ")" ::: "memory");     \
  __builtin_amdgcn_sched_barrier(0);                         \
  __builtin_amdgcn_s_barrier();                              \
  __builtin_amdgcn_sched_barrier(0);

#define BODY(CB)                                                               \
  {                                                                            \
    const short* Lb = lds + (CB) * 12288;                                      \
    bf16x8 a[4], b[8];                                                         \
    _Pragma("unroll") for (int mi = 0; mi < 4; mi++)                           \
        a[mi] = *(const bf16x8*)(Lb + aoff + mi * 512);                        \
    _Pragma("unroll") for (int nj = 0; nj < 8; nj++)                           \
        b[nj] = *(const bf16x8*)(Lb + boff + nj * 512);                        \
    __builtin_amdgcn_s_setprio(1);                                             \
    _Pragma("unroll") for (int mi = 0; mi < 4; mi++)                           \
        _Pragma("unroll") for (int nj = 0; nj < 8; nj++) acc[mi][nj] =         \
            __builtin_amdgcn_mfma_f32_16x16x32_bf16(a[mi], b[nj], acc[mi][nj], \
                                                    0, 0, 0);                  \
    __builtin_amdgcn_s_setprio(0);                                             \
  }

  const int NKT = K >> 5;
  STAGE(0, 0)
  STAGE(1, 1)

  int cb = 0, sb = 2;
  for (int kt = 0; kt < NKT - 1; ++kt) {
    TILE_WAIT(6)
    if (kt + 2 < NKT) STAGE(sb, kt + 2)
    BODY(cb)
    cb = (cb == 2) ? 0 : cb + 1;
    sb = (sb == 2) ? 0 : sb + 1;
  }
  TILE_WAIT(0)
  BODY(cb)
#undef STAGE
#undef TILE_WAIT
#undef BODY

  float bv[8];
#pragma unroll
  for (int nj = 0; nj < 8; nj++) bv[nj] = bias[n0 + wn + nj * 16 + lr];

#pragma unroll
  for (int mi = 0; mi < 4; mi++)
#pragma unroll
    for (int i = 0; i < 4; i++) {
      const long row = m0 + wm + mi * 16 + lg * 4 + i;
      const long rb = row * ldc + n0 + wn + lr;
      short* p = (short*)Cout + rb;
#pragma unroll
      for (int nj = 0; nj < 8; nj++) p[nj * 16] = f2b(gelu_f(acc[mi][nj][i] + bv[nj]));
    }
}

// ======== 128x512 fused GEMM + residual + LayerNorm (proj+LN1, fc2+LN2) =====
// 512 threads = 8 waves (2M x 4N); per-wave 64x128 (acc[4][8]). BK=32,
// 3-ring (120 KiB), distance 2, vmcnt(5) (5 loads/tile). r7 chunk-XOR swizzle.
// Epilogue: pre = acc+bias+b2f(res); row stats via shfl over lr (128 cols/wave)
// + 4 KiB LDS cross-wave table (4 wn waves); LN applied in-register.
// EPI 0: out bf16 (H) | 1: out f32 (final output).
template <int EPI>
__global__ __launch_bounds__(512, 1) void gemm_ln(
    const short* __restrict__ A, const short* __restrict__ Bt,
    const float* __restrict__ bias, const short* __restrict__ res,
    const float* __restrict__ gamma, const float* __restrict__ beta,
    void* __restrict__ Cout, int K) {
  __shared__ short lds[3 * 20480];  // per buffer: A 4096 | B 16384 shorts
  const int t = threadIdx.x;
  const int w = t >> 6, lane = t & 63;
  const int lr = lane & 15, lg = lane >> 4;
  const int wm = (w >> 2) * 64, wn = (w & 3) * 128;

  const int nwg = gridDim.x;
  const int orig = blockIdx.x;
  const int q = nwg >> 3, r = nwg & 7, xcd = orig & 7, idx = orig >> 3;
  const int swz = (xcd < r ? xcd * (q + 1) : r * (q + 1) + (xcd - r) * q) + idx;
  const long m0 = (long)swz * 128;

  f32x4 acc[4][8];
#pragma unroll
  for (int i = 0; i < 4; i++)
#pragma unroll
    for (int j = 0; j < 8; j++) acc[i][j] = f32x4{0.f, 0.f, 0.f, 0.f};

  // staging: A row = t>>2 (0..127), B rows = t>>2 + 128*l; chunk = t&3,
  // pre-swizzled source chunk = (t&3)^((row>>1)&3) = (t&3)^((t>>3)&3)
  // (128*l contributes 0 mod 4 to row>>1).
  const int srow = t >> 2;
  const int schunk = (t & 3) ^ ((t >> 3) & 3);
  const short* Ag = A + (m0 + srow) * (long)K + schunk * 8;
  const short* Bg = Bt + (long)srow * K + schunk * 8;
  const long q128 = (long)128 * K;

#define STAGE(b, kt)                                        \
  {                                                         \
    short* d = lds + (b) * 20480 + t * 8;                   \
    gload16(Ag + (long)(kt) * 32, d);                       \
    short* db = d + 4096;                                   \
    gload16(Bg + (long)(kt) * 32, db);                      \
    gload16(Bg + q128 + (long)(kt) * 32, db + 4096);        \
    gload16(Bg + 2 * q128 + (long)(kt) * 32, db + 8192);    \
    gload16(Bg + 3 * q128 + (long)(kt) * 32, db + 12288);   \
  }

  const int xsw = (lg ^ ((lr >> 1) & 3)) * 8;
  const int aoff = (wm + lr) * 32 + xsw;
  const int boff = 4096 + (wn + lr) * 32 + xsw;

#define TILE_WAIT(WN)                                        \
  asm volatile("s_waitcnt vmcnt(" #WN ")" ::: "memory");     \
  __builtin_amdgcn_sched_barrier(0);                         \
  __builtin_amdgcn_s_barrier();                              \
  __builtin_amdgcn_sched_barrier(0);

#define BODY(CB)                                                               \
  {                                                                            \
    const short* Lb = lds + (CB) * 20480;                                      \
    bf16x8 a[4], b[8];                                                         \
    _Pragma("unroll") for (int mi = 0; mi < 4; mi++)                           \
        a[mi] = *(const bf16x8*)(Lb + aoff + mi * 512);                        \
    _Pragma("unroll") for (int nj = 0; nj < 8; nj++)                           \
        b[nj] = *(const bf16x8*)(Lb + boff + nj * 512);                        \
    __builtin_amdgcn_s_setprio(1);                                             \
    _Pragma("unroll") for (int mi = 0; mi < 4; mi++)                           \
        _Pragma("unroll") for (int nj = 0; nj < 8; nj++) acc[mi][nj] =         \
            __builtin_amdgcn_mfma_f32_16x16x32_bf16(a[mi], b[nj], acc[mi][nj], \
                                                    0, 0, 0);                  \
    __builtin_amdgcn_s_setprio(0);                                             \
  }

  const int NKT = K >> 5;
  STAGE(0, 0)
  STAGE(1, 1)

  int cb = 0, sb = 2;
  for (int kt = 0; kt < NKT - 1; ++kt) {
    TILE_WAIT(5)
    if (kt + 2 < NKT) STAGE(sb, kt + 2)
    BODY(cb)
    cb = (cb == 2) ? 0 : cb + 1;
    sb = (sb == 2) ? 0 : sb + 1;
  }
  TILE_WAIT(0)
  BODY(cb)
#undef STAGE
#undef TILE_WAIT
#undef BODY

  // ---- fused residual + LayerNorm epilogue ----
  float bvv[8], gv[8], btv[8];
#pragma unroll
  for (int nj = 0; nj < 8; nj++) {
    int col = wn + nj * 16 + lr;
    bvv[nj] = bias[col];
    gv[nj] = gamma[col];
    btv[nj] = beta[col];
  }

  __syncthreads();  // all LDS tile reads done; reuse lds for stats
  float* sums = (float*)lds;  // [128 rows][4 wn][2]

#pragma unroll
  for (int mi = 0; mi < 4; mi++)
#pragma unroll
    for (int i = 0; i < 4; i++) {
      const int row = wm + mi * 16 + lg * 4 + i;
      const long rb = (m0 + row) * 512 + wn + lr;
      const short* rp = res + rb;
      float s = 0.f, s2 = 0.f;
#pragma unroll
      for (int nj = 0; nj < 8; nj++) {
        float v = acc[mi][nj][i] + bvv[nj] + b2f(rp[nj * 16]);
        acc[mi][nj][i] = v;
        s += v;
        s2 += v * v;
      }
#pragma unroll
      for (int off = 1; off < 16; off <<= 1) {
        s += __shfl_xor(s, off, 64);
        s2 += __shfl_xor(s2, off, 64);
      }
      if (lr == 0) {
        float* p = sums + (row * 4 + (w & 3)) * 2;
        p[0] = s;
        p[1] = s2;
      }
    }
  __syncthreads();

#pragma unroll
  for (int mi = 0; mi < 4; mi++)
#pragma unroll
    for (int i = 0; i < 4; i++) {
      const int row = wm + mi * 16 + lg * 4 + i;
      const float* p = sums + row * 8;
      float S = p[0] + p[2] + p[4] + p[6];
      float S2 = p[1] + p[3] + p[5] + p[7];
      float mu = S * (1.f / 512.f);
      float var = S2 * (1.f / 512.f) - mu * mu;
      float rstd = rsqrtf(fmaxf(var, 0.f) + 1e-12f);
      const long rb = (m0 + row) * 512 + wn + lr;
      if (EPI == 0) {
        short* o = (short*)Cout + rb;
#pragma unroll
        for (int nj = 0; nj < 8; nj++)
          o[nj * 16] = f2b(gv[nj] * ((acc[mi][nj][i] - mu) * rstd) + btv[nj]);
      } else {
        float* o = (float*)Cout + rb;
#pragma unroll
        for (int nj = 0; nj < 8; nj++)
          o[nj * 16] = gv[nj] * ((acc[mi][nj][i] - mu) * rstd) + btv[nj];
      }
    }
}

// ============ 256x256 8-phase GEMM (QKV) ============
#define DSR(d, a, OFF) \
  asm volatile("ds_read_b128 %0, %1 offset:" OFF : "=v"(d) : "v"(a))
#define SB __builtin_amdgcn_sched_barrier(0)

template <int EPI>  // 0: bf16 v+bias
__global__ __launch_bounds__(512, 1) void gemm256(
    const short* __restrict__ A, const short* __restrict__ Bt,
    const float* __restrict__ bias, const short* __restrict__ resB,
    void* __restrict__ Cout, int K, int ldc, int gxN) {
  extern __shared__ short lds[];
  const int t = threadIdx.x;
  const int lane = t & 63, w = t >> 6;
  const int lr = lane & 15, lg = lane >> 4;
  const int wm = w >> 2, wn = w & 3;

  const int nwg = gridDim.x, orig = blockIdx.x;
  const int q8 = nwg >> 3, r8 = nwg & 7, xcd = orig & 7, idx = orig >> 3;
  const int swz = (xcd < r8 ? xcd * (q8 + 1) : r8 * (q8 + 1) + (xcd - r8) * q8) + idx;
  const long m0 = (long)(swz / gxN) * 256;
  const int n0 = (swz % gxN) * 256;

  f32x4 acc[8][4];
#pragma unroll
  for (int i = 0; i < 8; i++)
#pragma unroll
    for (int j = 0; j < 4; j++) acc[i][j] = f32x4{0.f, 0.f, 0.f, 0.f};

  const int srow = t >> 3;
  const int sch = (t & 7) ^ (srow & 7);
  const short* sA = A + (m0 + srow) * (long)K + sch * 8;
  const short* sB = Bt + ((long)n0 + srow) * K + sch * 8;
  const long r64 = (long)64 * K;

#define STG_A(tt, h)                                                     \
  {                                                                      \
    short* d_ = lds + ((tt) & 1) * 16384 + (h) * 8192 + t * 8;           \
    const short* s_ = sA + (h) * 2 * r64 + (long)(tt) * 64;              \
    gload16(s_, d_);                                                     \
    gload16(s_ + r64, d_ + 4096);                                        \
  }
#define STG_B(tt, h)                                                     \
  {                                                                      \
    short* d_ = lds + 32768 + ((tt) & 1) * 16384 + (h) * 8192 + t * 8;   \
    const short* s_ = sB + (h) * 2 * r64 + (long)(tt) * 64;              \
    gload16(s_, d_);                                                     \
    gload16(s_ + r64, d_ + 4096);                                        \
  }

  const unsigned ldsB = (unsigned)(uintptr_t)lds;
  const unsigned xb0 = (unsigned)((lg ^ (lr & 7)) * 16);
  const unsigned xb1 = (unsigned)(((4 + lg) ^ (lr & 7)) * 16);
  const unsigned aRowB = (unsigned)((wm * 128 + lr) * 128);
  const unsigned bRowB = 65536u + (unsigned)((wn * 64 + lr) * 128);

#define BAR                                  \
  {                                          \
    SB;                                      \
    __builtin_amdgcn_s_barrier();            \
    SB;                                      \
  }
#define LGKM0 asm volatile("s_waitcnt lgkmcnt(0)")

  const int NT = K >> 6;
  STG_A(0, 0) STG_A(0, 1) STG_B(0, 0) STG_B(0, 1) STG_B(1, 0) STG_B(1, 1)
  asm volatile("s_waitcnt vmcnt(4)" ::: "memory");
  BAR

#define MFMA8(AC, A0, A1)                                                      \
  {                                                                            \
    __builtin_amdgcn_s_setprio(1);                                             \
    acc[AC][0] = __builtin_amdgcn_mfma_f32_16x16x32_bf16(A0, b00, acc[AC][0], 0, 0, 0); \
    acc[AC][0] = __builtin_amdgcn_mfma_f32_16x16x32_bf16(A1, b01, acc[AC][0], 0, 0, 0); \
    acc[AC][1] = __builtin_amdgcn_mfma_f32_16x16x32_bf16(A0, b10, acc[AC][1], 0, 0, 0); \
    acc[AC][1] = __builtin_amdgcn_mfma_f32_16x16x32_bf16(A1, b11, acc[AC][1], 0, 0, 0); \
    acc[AC][2] = __builtin_amdgcn_mfma_f32_16x16x32_bf16(A0, b20, acc[AC][2], 0, 0, 0); \
    acc[AC][2] = __builtin_amdgcn_mfma_f32_16x16x32_bf16(A1, b21, acc[AC][2], 0, 0, 0); \
    acc[AC][3] = __builtin_amdgcn_mfma_f32_16x16x32_bf16(A0, b30, acc[AC][3], 0, 0, 0); \
    acc[AC][3] = __builtin_amdgcn_mfma_f32_16x16x32_bf16(A1, b31, acc[AC][3], 0, 0, 0); \
    __builtin_amdgcn_s_setprio(0);                                             \
  }

  for (int tt = 0; tt < NT; ++tt) {
    const unsigned dAb = (unsigned)((tt & 1) * 32768);
    const unsigned aA0 = ldsB + aRowB + xb0 + dAb;
    const unsigned aA1 = ldsB + aRowB + xb1 + dAb;
    const unsigned bA0 = ldsB + bRowB + xb0 + dAb;
    const unsigned bA1 = ldsB + bRowB + xb1 + dAb;
    bf16x8 b00, b01, b10, b11, b20, b21, b30, b31;

    {
      DSR(b00, bA0, "0");    DSR(b01, bA1, "0");
      DSR(b10, bA0, "2048"); DSR(b11, bA1, "2048");
      DSR(b20, bA0, "4096"); DSR(b21, bA1, "4096");
      DSR(b30, bA0, "6144"); DSR(b31, bA1, "6144");
      bf16x8 a00, a01, a10, a11;
      DSR(a00, aA0, "0");    DSR(a01, aA1, "0");
      DSR(a10, aA0, "2048"); DSR(a11, aA1, "2048");
      SB;
      if (tt + 1 < NT) STG_A(tt + 1, 0)
      BAR
      LGKM0; SB;
      MFMA8(0, a00, a01)
      MFMA8(1, a10, a11)
      BAR
    }
    {
      bf16x8 a00, a01, a10, a11;
      DSR(a00, aA0, "4096"); DSR(a01, aA1, "4096");
      DSR(a10, aA0, "6144"); DSR(a11, aA1, "6144");
      SB;
      if (tt + 1 < NT) STG_A(tt + 1, 1)
      BAR
      LGKM0; SB;
      MFMA8(2, a00, a01)
      MFMA8(3, a10, a11)
      BAR
    }
    {
      bf16x8 a00, a01, a10, a11;
      DSR(a00, aA0, "8192");  DSR(a01, aA1, "8192");
      DSR(a10, aA0, "10240"); DSR(a11, aA1, "10240");
      SB;
      if (tt + 2 < NT) STG_B(tt + 2, 0)
      BAR
      LGKM0; SB;
      MFMA8(4, a00, a01)
      MFMA8(5, a10, a11)
      BAR
    }
    {
      bf16x8 a00, a01, a10, a11;
      DSR(a00, aA0, "12288"); DSR(a01, aA1, "12288");
      DSR(a10, aA0, "14336"); DSR(a11, aA1, "14336");
      SB;
      if (tt + 2 < NT) STG_B(tt + 2, 1)
      BAR
      LGKM0; SB;
      MFMA8(6, a00, a01)
      MFMA8(7, a10, a11)
      if (tt + 2 < NT) {
        asm volatile("s_waitcnt vmcnt(4)" ::: "memory");
      } else if (tt + 1 < NT) {
        asm volatile("s_waitcnt vmcnt(0)" ::: "memory");
      }
      BAR
    }
  }
#undef MFMA8
#undef STG_A
#undef STG_B

  float bv[4];
#pragma unroll
  for (int nj = 0; nj < 4; nj++) bv[nj] = bias[n0 + wn * 64 + nj * 16 + lr];

#pragma unroll
  for (int a = 0; a < 8; a++)
#pragma unroll
    for (int i = 0; i < 4; i++) {
      const long row = m0 + wm * 128 + a * 16 + lg * 4 + i;
      const long rb = row * ldc + n0 + wn * 64 + lr;
      short* p = (short*)Cout + rb;
      if (EPI == 0) {
#pragma unroll
        for (int nj = 0; nj < 4; nj++) p[nj * 16] = f2b(acc[a][nj][i] + bv[nj]);
      } else {
        const short* rp = resB + rb;
#pragma unroll
        for (int nj = 0; nj < 4; nj++)
          p[nj * 16] = f2b(acc[a][nj][i] + bv[nj] + b2f(rp[nj * 16]));
      }
    }
}
#undef DSR
#undef SB
#undef BAR
#undef LGKM0

// ---------------- windowed attention ----------------
__global__ __launch_bounds__(256, 2) void attn_win(const short* __restrict__ QKV,
                                                   short* __restrict__ AO) {
  __shared__ short Vs[64 * 72];
  __shared__ short Vt[64 * 72];
  __shared__ short Ps[64 * 72];
  const int t = threadIdx.x, w = t >> 6, lane = t & 63;
  const int lr = lane & 15, lg = lane >> 4;
  const long base = (long)blockIdx.x * 64 * 1536;
  const long obase = (long)blockIdx.x * 64 * 512;

  for (int h = 0; h < 8; h++) {
    const int co = h * 64;
#pragma unroll
    for (int it = 0; it < 2; it++) {
      int c = t + it * 256;
      int j = c >> 3, d0 = (c & 7) * 8;
      *(bf16x8*)(Vs + j * 72 + d0) =
          *(const bf16x8*)(QKV + base + (long)j * 1536 + 1024 + co + d0);
    }
    bf16x8 qf[2], kf[4][2];
#pragma unroll
    for (int kb = 0; kb < 2; kb++)
      qf[kb] = *(const bf16x8*)(QKV + base + (long)(w * 16 + lr) * 1536 + co + kb * 32 + lg * 8);
#pragma unroll
    for (int nj = 0; nj < 4; nj++)
#pragma unroll
      for (int kb = 0; kb < 2; kb++)
        kf[nj][kb] = *(const bf16x8*)(QKV + base + (long)(nj * 16 + lr) * 1536 + 512 + co +
                                      kb * 32 + lg * 8);
    __syncthreads();  // Vs ready

#pragma unroll
    for (int it2 = 0; it2 < 2; it2++) {
      int d = t & 63;
      int j0 = ((t >> 6) + it2 * 4) * 8;
      bf16x8 tmp;
#pragma unroll
      for (int jj = 0; jj < 8; jj++) tmp[jj] = Vs[(j0 + jj) * 72 + d];
      *(bf16x8*)(Vt + d * 72 + j0) = tmp;
    }

    f32x4 s[4];
#pragma unroll
    for (int nj = 0; nj < 4; nj++) {
      s[nj] = f32x4{0.f, 0.f, 0.f, 0.f};
      s[nj] = __builtin_amdgcn_mfma_f32_16x16x32_bf16(qf[0], kf[nj][0], s[nj], 0, 0, 0);
      s[nj] = __builtin_amdgcn_mfma_f32_16x16x32_bf16(qf[1], kf[nj][1], s[nj], 0, 0, 0);
      s[nj] = s[nj] * 0.125f;
    }

#pragma unroll
    for (int i = 0; i < 4; i++) {
      float mx = fmaxf(fmaxf(s[0][i], s[1][i]), fmaxf(s[2][i], s[3][i]));
#pragma unroll
      for (int off = 1; off < 16; off <<= 1) mx = fmaxf(mx, __shfl_xor(mx, off, 64));
      float sum = 0.f;
#pragma unroll
      for (int nj = 0; nj < 4; nj++) {
        float p = __expf(s[nj][i] - mx);
        s[nj][i] = p;
        sum += p;
      }
#pragma unroll
      for (int off = 1; off < 16; off <<= 1) sum += __shfl_xor(sum, off, 64);
      float inv = 1.f / sum;
#pragma unroll
      for (int nj = 0; nj < 4; nj++) s[nj][i] *= inv;
    }

#pragma unroll
    for (int nj = 0; nj < 4; nj++)
#pragma unroll
      for (int i = 0; i < 4; i++)
        Ps[(w * 16 + lg * 4 + i) * 72 + nj * 16 + lr] = f2b(s[nj][i]);

    __syncthreads();  // Vt ready

    bf16x8 pa[2];
#pragma unroll
    for (int kb = 0; kb < 2; kb++)
      pa[kb] = *(const bf16x8*)(Ps + (w * 16 + lr) * 72 + kb * 32 + lg * 8);

    f32x4 o[4];
#pragma unroll
    for (int nb = 0; nb < 4; nb++) o[nb] = f32x4{0.f, 0.f, 0.f, 0.f};
#pragma unroll
    for (int kb = 0; kb < 2; kb++)
#pragma unroll
      for (int nb = 0; nb < 4; nb++) {
        bf16x8 vb = *(const bf16x8*)(Vt + (nb * 16 + lr) * 72 + kb * 32 + lg * 8);
        o[nb] = __builtin_amdgcn_mfma_f32_16x16x32_bf16(pa[kb], vb, o[nb], 0, 0, 0);
      }

#pragma unroll
    for (int nb = 0; nb < 4; nb++)
#pragma unroll
      for (int i = 0; i < 4; i++)
        AO[obase + (long)(w * 16 + lg * 4 + i) * 512 + co + nb * 16 + lr] = f2b(o[nb][i]);
    __syncthreads();
  }
}

// ---------------- driver ----------------
extern "C" void kernel_launch(void* const* d_in, const int* in_sizes, int n_in,
                              void* d_out, int out_size, void* d_ws, size_t ws_size,
                              hipStream_t stream) {
  (void)in_sizes; (void)n_in; (void)out_size;
  const float* x = (const float*)d_in[0];
  const float* wq = (const float*)d_in[1];
  const float* bq = (const float*)d_in[2];
  const float* wk = (const float*)d_in[3];
  const float* bk = (const float*)d_in[4];
  const float* wv = (const float*)d_in[5];
  const float* bv = (const float*)d_in[6];
  const float* wo = (const float*)d_in[7];
  const float* bo = (const float*)d_in[8];
  const float* g1 = (const float*)d_in[9];
  const float* be1 = (const float*)d_in[10];
  const float* wfc1 = (const float*)d_in[11];
  const float* bfc1 = (const float*)d_in[12];
  const float* wfc2 = (const float*)d_in[13];
  const float* bfc2 = (const float*)d_in[14];
  const float* g2 = (const float*)d_in[15];
  const float* be2 = (const float*)d_in[16];

  const long T = 65536;
  char* ws = (char*)d_ws;

  short* WQKVT = (short*)(ws);                 // [1536][512]
  short* WOT = WQKVT + 1536 * 512;             // [512][512]
  short* WFC1T = WOT + 512 * 512;              // [2048][512]
  short* WFC2T = WFC1T + 2048 * 512;           // [512][2048]
  float* BQKV = (float*)(WFC2T + 512 * 2048);  // [1536]
  size_t woff = ((size_t)((char*)(BQKV + 1536) - ws) + 255) & ~(size_t)255;

  size_t avail = (ws_size > woff) ? (ws_size - woff) : 0;
  long Tc = T;
  while (Tc > 256 && (size_t)Tc * 7168 > avail) Tc >>= 1;
  const long nch = T / Tc;

  char* R0 = ws + woff;                // QKV bf16 [Tc][1536] / FF1 bf16 [Tc][2048]
  char* R1 = R0 + (size_t)Tc * 4096;   // XB bf16 (persists through proj)
  char* R1b = R1 + (size_t)Tc * 1024;  // AO bf16
  char* R2 = R1b + (size_t)Tc * 1024;  // H bf16

  short* QKV = (short*)R0;
  short* FF1 = (short*)R0;
  short* XB = (short*)R1;
  short* AO = (short*)R1b;
  short* H = (short*)R2;

  pack_all<<<3073, 256, 0, stream>>>(wq, wk, wv, wo, wfc1, wfc2, bq, bk, bv,
                                     WQKVT, WOT, WFC1T, WFC2T, BQKV);

  const size_t LDSB = 131072;
  for (long c = 0; c < nch; c++) {
    const long t0 = c * Tc;
    const int mb = (int)(Tc / 256);
    const int mb2 = (int)(Tc / 128);
    cvt_bf16_vec<<<(int)(Tc / 4), 256, 0, stream>>>(x + t0 * 512, XB, Tc * 512);
    // QKV projection (256^2 8-phase)
    gemm256<0><<<mb * 6, 512, LDSB, stream>>>(XB, WQKVT, BQKV, nullptr,
                                              (void*)QKV, 512, 1536, 6);
    attn_win<<<(int)(Tc / 64), 256, 0, stream>>>(QKV, AO);
    // FUSED: attn-out proj + XB residual + LN1 -> H (bf16)
    gemm_ln<0><<<mb2, 512, 0, stream>>>(AO, WOT, bo, XB, g1, be1, (void*)H, 512);
    // fc1 + GELU (128x256 ring)
    gemm_bt2<1><<<mb2 * 8, 256, 0, stream>>>(H, WFC1T, bfc1, (void*)FF1, 512, 2048, 8);
    // FUSED: fc2 + H residual + LN2 -> final f32 output
    gemm_ln<1><<<mb2, 512, 0, stream>>>(FF1, WFC2T, bfc2, H, g2, be2,
                                        (void*)((float*)d_out + t0 * 512), 2048);
  }
}

// Round 17
// 707.110 us; speedup vs baseline: 1.0512x; 1.0512x over previous
//
#include <hip/hip_runtime.h>
#include <hip/hip_bf16.h>

typedef __attribute__((ext_vector_type(8))) short bf16x8;
typedef __attribute__((ext_vector_type(4))) float f32x4;

__device__ __forceinline__ short f2b(float f) {
  return __builtin_bit_cast(short, __float2bfloat16(f));
}
__device__ __forceinline__ float b2f(short s) {
  unsigned u = ((unsigned)(unsigned short)s) << 16;
  return __builtin_bit_cast(float, u);
}

__device__ __forceinline__ void gload16(const void* g, void* l) {
  __builtin_amdgcn_global_load_lds(
      (const __attribute__((address_space(1))) void*)g,
      (__attribute__((address_space(3))) void*)l, 16, 0, 0);
}

// sigmoid-form GELU: v*sigmoid(1.702v)
__device__ __forceinline__ float gelu_f(float v) {
  float e = __builtin_amdgcn_exp2f(-2.45537082f * v);
  return v * __builtin_amdgcn_rcpf(1.f + e);
}

// ---------------- packing kernels ----------------
__global__ void cvt_bf16_vec(const float* __restrict__ src, short* __restrict__ dst, long n) {
  long i = ((long)blockIdx.x * 256 + threadIdx.x) * 8;
  if (i >= n) return;
  f32x4 a = *(const f32x4*)(src + i);
  f32x4 b = *(const f32x4*)(src + i + 4);
  bf16x8 o;
#pragma unroll
  for (int j = 0; j < 4; j++) o[j] = f2b(a[j]);
#pragma unroll
  for (int j = 0; j < 4; j++) o[j + 4] = f2b(b[j]);
  *(bf16x8*)(dst + i) = o;
}

// All 6 weight transposes + bias pack in ONE launch.
__global__ void pack_all(const float* __restrict__ wq, const float* __restrict__ wk,
                         const float* __restrict__ wv, const float* __restrict__ wo,
                         const float* __restrict__ wfc1, const float* __restrict__ wfc2,
                         const float* __restrict__ bq, const float* __restrict__ bk,
                         const float* __restrict__ bv,
                         short* __restrict__ WQKVT, short* __restrict__ WOT,
                         short* __restrict__ WFC1T, short* __restrict__ WFC2T,
                         float* __restrict__ BQKV) {
  const int b = blockIdx.x;
  if (b >= 3072) {  // bias block
    for (int t = threadIdx.x; t < 1536; t += 256)
      BQKV[t] = (t < 512) ? bq[t] : ((t < 1024) ? bk[t - 512] : bv[t - 1024]);
    return;
  }
  __shared__ float tile[32][33];
  const float* src;
  short* dst;
  int K, N, tb;
  if (b < 256)       { src = wq;   dst = WQKVT;              K = 512;  N = 512;  tb = b; }
  else if (b < 512)  { src = wk;   dst = WQKVT + 512 * 512;  K = 512;  N = 512;  tb = b - 256; }
  else if (b < 768)  { src = wv;   dst = WQKVT + 1024 * 512; K = 512;  N = 512;  tb = b - 512; }
  else if (b < 1024) { src = wo;   dst = WOT;                K = 512;  N = 512;  tb = b - 768; }
  else if (b < 2048) { src = wfc1; dst = WFC1T;              K = 512;  N = 2048; tb = b - 1024; }
  else               { src = wfc2; dst = WFC2T;              K = 2048; N = 512;  tb = b - 2048; }
  const int ntx = N >> 5;
  const int n0 = (tb % ntx) * 32, k0 = (tb / ntx) * 32;
  const int j = threadIdx.x & 31, i0 = threadIdx.x >> 5;
#pragma unroll
  for (int r = 0; r < 4; r++) {
    int i = i0 + r * 8;
    tile[i][j] = src[(long)(k0 + i) * N + n0 + j];
  }
  __syncthreads();
#pragma unroll
  for (int r = 0; r < 4; r++) {
    int i = i0 + r * 8;
    dst[(long)(n0 + i) * K + k0 + j] = f2b(tile[j][i]);
  }
}

// ======== 128x256 ring GEMM (fc1) — per-wave 64x128, BK=32, 3-buf ring =====
template <int EPI>  // 1: bf16 gelu(v+bias)
__global__ __launch_bounds__(256, 2) void gemm_bt2(
    const short* __restrict__ A, const short* __restrict__ Bt,
    const float* __restrict__ bias, void* __restrict__ Cout, int K, int ldc, int gxN) {
  __shared__ short lds[3 * 12288];
  const int t = threadIdx.x;
  const int w = t >> 6, lane = t & 63;
  const int lr = lane & 15, lg = lane >> 4;

  const int nwg = gridDim.x;
  const int orig = blockIdx.x;
  const int q = nwg >> 3, r = nwg & 7, xcd = orig & 7, idx = orig >> 3;
  const int swz = (xcd < r ? xcd * (q + 1) : r * (q + 1) + (xcd - r) * q) + idx;
  const long m0 = (long)(swz / gxN) * 128;
  const int n0 = (swz % gxN) * 256;

  const int wm = (w >> 1) * 64, wn = (w & 1) * 128;

  f32x4 acc[4][8];
#pragma unroll
  for (int i = 0; i < 4; i++)
#pragma unroll
    for (int j = 0; j < 8; j++) acc[i][j] = f32x4{0.f, 0.f, 0.f, 0.f};

  const int srow = t >> 2;
  const int schunk = (t & 3) ^ ((t >> 3) & 3);
  const short* Ag = A + (m0 + srow) * (long)K + schunk * 8;
  const short* Bg = Bt + ((long)n0 + srow) * K + schunk * 8;
  const long half = (long)64 * K;

#define STAGE(b, kt)                                       \
  {                                                        \
    short* d = lds + (b) * 12288 + t * 8;                  \
    gload16(Ag + (long)(kt) * 32, d);                      \
    gload16(Ag + half + (long)(kt) * 32, d + 2048);        \
    short* db = d + 4096;                                  \
    gload16(Bg + (long)(kt) * 32, db);                     \
    gload16(Bg + half + (long)(kt) * 32, db + 2048);       \
    gload16(Bg + 2 * half + (long)(kt) * 32, db + 4096);   \
    gload16(Bg + 3 * half + (long)(kt) * 32, db + 6144);   \
  }

  const int xsw = (lg ^ ((lr >> 1) & 3)) * 8;
  const int aoff = (wm + lr) * 32 + xsw;
  const int boff = 4096 + (wn + lr) * 32 + xsw;

#define TILE_WAIT(WN)                                        \
  asm volatile("s_waitcnt vmcnt(" #WN ")" ::: "memory");     \
  __builtin_amdgcn_sched_barrier(0);                         \
  __builtin_amdgcn_s_barrier();                              \
  __builtin_amdgcn_sched_barrier(0);

#define BODY(CB)                                                               \
  {                                                                            \
    const short* Lb = lds + (CB) * 12288;                                      \
    bf16x8 a[4], b[8];                                                         \
    _Pragma("unroll") for (int mi = 0; mi < 4; mi++)                           \
        a[mi] = *(const bf16x8*)(Lb + aoff + mi * 512);                        \
    _Pragma("unroll") for (int nj = 0; nj < 8; nj++)                           \
        b[nj] = *(const bf16x8*)(Lb + boff + nj * 512);                        \
    __builtin_amdgcn_s_setprio(1);                                             \
    _Pragma("unroll") for (int mi = 0; mi < 4; mi++)                           \
        _Pragma("unroll") for (int nj = 0; nj < 8; nj++) acc[mi][nj] =         \
            __builtin_amdgcn_mfma_f32_16x16x32_bf16(a[mi], b[nj], acc[mi][nj], \
                                                    0, 0, 0);                  \
    __builtin_amdgcn_s_setprio(0);                                             \
  }

  const int NKT = K >> 5;
  STAGE(0, 0)
  STAGE(1, 1)

  int cb = 0, sb = 2;
  for (int kt = 0; kt < NKT - 1; ++kt) {
    TILE_WAIT(6)
    if (kt + 2 < NKT) STAGE(sb, kt + 2)
    BODY(cb)
    cb = (cb == 2) ? 0 : cb + 1;
    sb = (sb == 2) ? 0 : sb + 1;
  }
  TILE_WAIT(0)
  BODY(cb)
#undef STAGE
#undef TILE_WAIT
#undef BODY

  float bv[8];
#pragma unroll
  for (int nj = 0; nj < 8; nj++) bv[nj] = bias[n0 + wn + nj * 16 + lr];

#pragma unroll
  for (int mi = 0; mi < 4; mi++)
#pragma unroll
    for (int i = 0; i < 4; i++) {
      const long row = m0 + wm + mi * 16 + lg * 4 + i;
      const long rb = row * ldc + n0 + wn + lr;
      short* p = (short*)Cout + rb;
#pragma unroll
      for (int nj = 0; nj < 8; nj++) p[nj * 16] = f2b(gelu_f(acc[mi][nj][i] + bv[nj]));
    }
}

// ============ 256x256 8-phase GEMM (QKV/proj/fc2) ============
// EPI 0: bf16 v+bias | 2: bf16 v+bias+b2f(resB)
#define DSR(d, a, OFF) \
  asm volatile("ds_read_b128 %0, %1 offset:" OFF : "=v"(d) : "v"(a))
#define SB __builtin_amdgcn_sched_barrier(0)

template <int EPI>
__global__ __launch_bounds__(512, 1) void gemm256(
    const short* __restrict__ A, const short* __restrict__ Bt,
    const float* __restrict__ bias, const short* __restrict__ resB,
    void* __restrict__ Cout, int K, int ldc, int gxN) {
  extern __shared__ short lds[];
  const int t = threadIdx.x;
  const int lane = t & 63, w = t >> 6;
  const int lr = lane & 15, lg = lane >> 4;
  const int wm = w >> 2, wn = w & 3;

  const int nwg = gridDim.x, orig = blockIdx.x;
  const int q8 = nwg >> 3, r8 = nwg & 7, xcd = orig & 7, idx = orig >> 3;
  const int swz = (xcd < r8 ? xcd * (q8 + 1) : r8 * (q8 + 1) + (xcd - r8) * q8) + idx;
  const long m0 = (long)(swz / gxN) * 256;
  const int n0 = (swz % gxN) * 256;

  f32x4 acc[8][4];
#pragma unroll
  for (int i = 0; i < 8; i++)
#pragma unroll
    for (int j = 0; j < 4; j++) acc[i][j] = f32x4{0.f, 0.f, 0.f, 0.f};

  const int srow = t >> 3;
  const int sch = (t & 7) ^ (srow & 7);
  const short* sA = A + (m0 + srow) * (long)K + sch * 8;
  const short* sB = Bt + ((long)n0 + srow) * K + sch * 8;
  const long r64 = (long)64 * K;

#define STG_A(tt, h)                                                     \
  {                                                                      \
    short* d_ = lds + ((tt) & 1) * 16384 + (h) * 8192 + t * 8;           \
    const short* s_ = sA + (h) * 2 * r64 + (long)(tt) * 64;              \
    gload16(s_, d_);                                                     \
    gload16(s_ + r64, d_ + 4096);                                        \
  }
#define STG_B(tt, h)                                                     \
  {                                                                      \
    short* d_ = lds + 32768 + ((tt) & 1) * 16384 + (h) * 8192 + t * 8;   \
    const short* s_ = sB + (h) * 2 * r64 + (long)(tt) * 64;              \
    gload16(s_, d_);                                                     \
    gload16(s_ + r64, d_ + 4096);                                        \
  }

  const unsigned ldsB = (unsigned)(uintptr_t)lds;
  const unsigned xb0 = (unsigned)((lg ^ (lr & 7)) * 16);
  const unsigned xb1 = (unsigned)(((4 + lg) ^ (lr & 7)) * 16);
  const unsigned aRowB = (unsigned)((wm * 128 + lr) * 128);
  const unsigned bRowB = 65536u + (unsigned)((wn * 64 + lr) * 128);

#define BAR                                  \
  {                                          \
    SB;                                      \
    __builtin_amdgcn_s_barrier();            \
    SB;                                      \
  }
#define LGKM0 asm volatile("s_waitcnt lgkmcnt(0)")

  const int NT = K >> 6;
  STG_A(0, 0) STG_A(0, 1) STG_B(0, 0) STG_B(0, 1) STG_B(1, 0) STG_B(1, 1)
  asm volatile("s_waitcnt vmcnt(4)" ::: "memory");
  BAR

#define MFMA8(AC, A0, A1)                                                      \
  {                                                                            \
    __builtin_amdgcn_s_setprio(1);                                             \
    acc[AC][0] = __builtin_amdgcn_mfma_f32_16x16x32_bf16(A0, b00, acc[AC][0], 0, 0, 0); \
    acc[AC][0] = __builtin_amdgcn_mfma_f32_16x16x32_bf16(A1, b01, acc[AC][0], 0, 0, 0); \
    acc[AC][1] = __builtin_amdgcn_mfma_f32_16x16x32_bf16(A0, b10, acc[AC][1], 0, 0, 0); \
    acc[AC][1] = __builtin_amdgcn_mfma_f32_16x16x32_bf16(A1, b11, acc[AC][1], 0, 0, 0); \
    acc[AC][2] = __builtin_amdgcn_mfma_f32_16x16x32_bf16(A0, b20, acc[AC][2], 0, 0, 0); \
    acc[AC][2] = __builtin_amdgcn_mfma_f32_16x16x32_bf16(A1, b21, acc[AC][2], 0, 0, 0); \
    acc[AC][3] = __builtin_amdgcn_mfma_f32_16x16x32_bf16(A0, b30, acc[AC][3], 0, 0, 0); \
    acc[AC][3] = __builtin_amdgcn_mfma_f32_16x16x32_bf16(A1, b31, acc[AC][3], 0, 0, 0); \
    __builtin_amdgcn_s_setprio(0);                                             \
  }

  for (int tt = 0; tt < NT; ++tt) {
    const unsigned dAb = (unsigned)((tt & 1) * 32768);
    const unsigned aA0 = ldsB + aRowB + xb0 + dAb;
    const unsigned aA1 = ldsB + aRowB + xb1 + dAb;
    const unsigned bA0 = ldsB + bRowB + xb0 + dAb;
    const unsigned bA1 = ldsB + bRowB + xb1 + dAb;
    bf16x8 b00, b01, b10, b11, b20, b21, b30, b31;

    {
      DSR(b00, bA0, "0");    DSR(b01, bA1, "0");
      DSR(b10, bA0, "2048"); DSR(b11, bA1, "2048");
      DSR(b20, bA0, "4096"); DSR(b21, bA1, "4096");
      DSR(b30, bA0, "6144"); DSR(b31, bA1, "6144");
      bf16x8 a00, a01, a10, a11;
      DSR(a00, aA0, "0");    DSR(a01, aA1, "0");
      DSR(a10, aA0, "2048"); DSR(a11, aA1, "2048");
      SB;
      if (tt + 1 < NT) STG_A(tt + 1, 0)
      BAR
      LGKM0; SB;
      MFMA8(0, a00, a01)
      MFMA8(1, a10, a11)
      BAR
    }
    {
      bf16x8 a00, a01, a10, a11;
      DSR(a00, aA0, "4096"); DSR(a01, aA1, "4096");
      DSR(a10, aA0, "6144"); DSR(a11, aA1, "6144");
      SB;
      if (tt + 1 < NT) STG_A(tt + 1, 1)
      BAR
      LGKM0; SB;
      MFMA8(2, a00, a01)
      MFMA8(3, a10, a11)
      BAR
    }
    {
      bf16x8 a00, a01, a10, a11;
      DSR(a00, aA0, "8192");  DSR(a01, aA1, "8192");
      DSR(a10, aA0, "10240"); DSR(a11, aA1, "10240");
      SB;
      if (tt + 2 < NT) STG_B(tt + 2, 0)
      BAR
      LGKM0; SB;
      MFMA8(4, a00, a01)
      MFMA8(5, a10, a11)
      BAR
    }
    {
      bf16x8 a00, a01, a10, a11;
      DSR(a00, aA0, "12288"); DSR(a01, aA1, "12288");
      DSR(a10, aA0, "14336"); DSR(a11, aA1, "14336");
      SB;
      if (tt + 2 < NT) STG_B(tt + 2, 1)
      BAR
      LGKM0; SB;
      MFMA8(6, a00, a01)
      MFMA8(7, a10, a11)
      if (tt + 2 < NT) {
        asm volatile("s_waitcnt vmcnt(4)" ::: "memory");
      } else if (tt + 1 < NT) {
        asm volatile("s_waitcnt vmcnt(0)" ::: "memory");
      }
      BAR
    }
  }
#undef MFMA8
#undef STG_A
#undef STG_B

  float bv[4];
#pragma unroll
  for (int nj = 0; nj < 4; nj++) bv[nj] = bias[n0 + wn * 64 + nj * 16 + lr];

#pragma unroll
  for (int a = 0; a < 8; a++)
#pragma unroll
    for (int i = 0; i < 4; i++) {
      const long row = m0 + wm * 128 + a * 16 + lg * 4 + i;
      const long rb = row * ldc + n0 + wn * 64 + lr;
      short* p = (short*)Cout + rb;
      if (EPI == 0) {
#pragma unroll
        for (int nj = 0; nj < 4; nj++) p[nj * 16] = f2b(acc[a][nj][i] + bv[nj]);
      } else {
        const short* rp = resB + rb;
#pragma unroll
        for (int nj = 0; nj < 4; nj++)
          p[nj * 16] = f2b(acc[a][nj][i] + bv[nj] + b2f(rp[nj * 16]));
      }
    }
}
#undef DSR
#undef SB
#undef BAR
#undef LGKM0

// ---------------- windowed attention ----------------
__global__ __launch_bounds__(256, 2) void attn_win(const short* __restrict__ QKV,
                                                   short* __restrict__ AO) {
  __shared__ short Vs[64 * 72];
  __shared__ short Vt[64 * 72];
  __shared__ short Ps[64 * 72];
  const int t = threadIdx.x, w = t >> 6, lane = t & 63;
  const int lr = lane & 15, lg = lane >> 4;
  const long base = (long)blockIdx.x * 64 * 1536;
  const long obase = (long)blockIdx.x * 64 * 512;

  for (int h = 0; h < 8; h++) {
    const int co = h * 64;
#pragma unroll
    for (int it = 0; it < 2; it++) {
      int c = t + it * 256;
      int j = c >> 3, d0 = (c & 7) * 8;
      *(bf16x8*)(Vs + j * 72 + d0) =
          *(const bf16x8*)(QKV + base + (long)j * 1536 + 1024 + co + d0);
    }
    bf16x8 qf[2], kf[4][2];
#pragma unroll
    for (int kb = 0; kb < 2; kb++)
      qf[kb] = *(const bf16x8*)(QKV + base + (long)(w * 16 + lr) * 1536 + co + kb * 32 + lg * 8);
#pragma unroll
    for (int nj = 0; nj < 4; nj++)
#pragma unroll
      for (int kb = 0; kb < 2; kb++)
        kf[nj][kb] = *(const bf16x8*)(QKV + base + (long)(nj * 16 + lr) * 1536 + 512 + co +
                                      kb * 32 + lg * 8);
    __syncthreads();  // Vs ready

#pragma unroll
    for (int it2 = 0; it2 < 2; it2++) {
      int d = t & 63;
      int j0 = ((t >> 6) + it2 * 4) * 8;
      bf16x8 tmp;
#pragma unroll
      for (int jj = 0; jj < 8; jj++) tmp[jj] = Vs[(j0 + jj) * 72 + d];
      *(bf16x8*)(Vt + d * 72 + j0) = tmp;
    }

    f32x4 s[4];
#pragma unroll
    for (int nj = 0; nj < 4; nj++) {
      s[nj] = f32x4{0.f, 0.f, 0.f, 0.f};
      s[nj] = __builtin_amdgcn_mfma_f32_16x16x32_bf16(qf[0], kf[nj][0], s[nj], 0, 0, 0);
      s[nj] = __builtin_amdgcn_mfma_f32_16x16x32_bf16(qf[1], kf[nj][1], s[nj], 0, 0, 0);
      s[nj] = s[nj] * 0.125f;
    }

#pragma unroll
    for (int i = 0; i < 4; i++) {
      float mx = fmaxf(fmaxf(s[0][i], s[1][i]), fmaxf(s[2][i], s[3][i]));
#pragma unroll
      for (int off = 1; off < 16; off <<= 1) mx = fmaxf(mx, __shfl_xor(mx, off, 64));
      float sum = 0.f;
#pragma unroll
      for (int nj = 0; nj < 4; nj++) {
        float p = __expf(s[nj][i] - mx);
        s[nj][i] = p;
        sum += p;
      }
#pragma unroll
      for (int off = 1; off < 16; off <<= 1) sum += __shfl_xor(sum, off, 64);
      float inv = 1.f / sum;
#pragma unroll
      for (int nj = 0; nj < 4; nj++) s[nj][i] *= inv;
    }

#pragma unroll
    for (int nj = 0; nj < 4; nj++)
#pragma unroll
      for (int i = 0; i < 4; i++)
        Ps[(w * 16 + lg * 4 + i) * 72 + nj * 16 + lr] = f2b(s[nj][i]);

    __syncthreads();  // Vt ready

    bf16x8 pa[2];
#pragma unroll
    for (int kb = 0; kb < 2; kb++)
      pa[kb] = *(const bf16x8*)(Ps + (w * 16 + lr) * 72 + kb * 32 + lg * 8);

    f32x4 o[4];
#pragma unroll
    for (int nb = 0; nb < 4; nb++) o[nb] = f32x4{0.f, 0.f, 0.f, 0.f};
#pragma unroll
    for (int kb = 0; kb < 2; kb++)
#pragma unroll
      for (int nb = 0; nb < 4; nb++) {
        bf16x8 vb = *(const bf16x8*)(Vt + (nb * 16 + lr) * 72 + kb * 32 + lg * 8);
        o[nb] = __builtin_amdgcn_mfma_f32_16x16x32_bf16(pa[kb], vb, o[nb], 0, 0, 0);
      }

#pragma unroll
    for (int nb = 0; nb < 4; nb++)
#pragma unroll
      for (int i = 0; i < 4; i++)
        AO[obase + (long)(w * 16 + lg * 4 + i) * 512 + co + nb * 16 + lr] = f2b(o[nb][i]);
    __syncthreads();
  }
}

// ---------------- LayerNorm over C=512, one row per wave ----------------
template <int INB, int OUTB>
__global__ __launch_bounds__(256, 4) void ln_rows(const float* __restrict__ Yf,
                                                  const short* __restrict__ Yb,
                                                  const float* __restrict__ gamma,
                                                  const float* __restrict__ beta,
                                                  short* __restrict__ Hb,
                                                  float* __restrict__ Of) {
  const int w = threadIdx.x >> 6, lane = threadIdx.x & 63;
  const long row = (long)blockIdx.x * 4 + w;
  float v[8];
  if (INB) {
    bf16x8 x = *(const bf16x8*)(Yb + row * 512 + lane * 8);
#pragma unroll
    for (int j = 0; j < 8; j++) v[j] = b2f(x[j]);
  } else {
    f32x4 a = *(const f32x4*)(Yf + row * 512 + lane * 8);
    f32x4 b = *(const f32x4*)(Yf + row * 512 + lane * 8 + 4);
#pragma unroll
    for (int j = 0; j < 4; j++) { v[j] = a[j]; v[j + 4] = b[j]; }
  }
  float s = 0.f, s2 = 0.f;
#pragma unroll
  for (int j = 0; j < 8; j++) { s += v[j]; s2 += v[j] * v[j]; }
#pragma unroll
  for (int off = 1; off < 64; off <<= 1) {
    s += __shfl_xor(s, off, 64);
    s2 += __shfl_xor(s2, off, 64);
  }
  float mu = s * (1.f / 512.f);
  float var = s2 * (1.f / 512.f) - mu * mu;
  float rstd = rsqrtf(fmaxf(var, 0.f) + 1e-12f);
  const int c0 = lane * 8;
  f32x4 ga = *(const f32x4*)(gamma + c0), gb = *(const f32x4*)(gamma + c0 + 4);
  f32x4 ba = *(const f32x4*)(beta + c0), bb = *(const f32x4*)(beta + c0 + 4);
  if (OUTB) {
    bf16x8 o;
#pragma unroll
    for (int j = 0; j < 4; j++) o[j] = f2b(ga[j] * ((v[j] - mu) * rstd) + ba[j]);
#pragma unroll
    for (int j = 0; j < 4; j++) o[j + 4] = f2b(gb[j] * ((v[j + 4] - mu) * rstd) + bb[j]);
    *(bf16x8*)(Hb + row * 512 + c0) = o;
  } else {
    f32x4 o0, o1;
#pragma unroll
    for (int j = 0; j < 4; j++) o0[j] = ga[j] * ((v[j] - mu) * rstd) + ba[j];
#pragma unroll
    for (int j = 0; j < 4; j++) o1[j] = gb[j] * ((v[j + 4] - mu) * rstd) + bb[j];
    *(f32x4*)(Of + row * 512 + c0) = o0;
    *(f32x4*)(Of + row * 512 + c0 + 4) = o1;
  }
}

// ---------------- driver ----------------
extern "C" void kernel_launch(void* const* d_in, const int* in_sizes, int n_in,
                              void* d_out, int out_size, void* d_ws, size_t ws_size,
                              hipStream_t stream) {
  (void)in_sizes; (void)n_in; (void)out_size;
  const float* x = (const float*)d_in[0];
  const float* wq = (const float*)d_in[1];
  const float* bq = (const float*)d_in[2];
  const float* wk = (const float*)d_in[3];
  const float* bk = (const float*)d_in[4];
  const float* wv = (const float*)d_in[5];
  const float* bv = (const float*)d_in[6];
  const float* wo = (const float*)d_in[7];
  const float* bo = (const float*)d_in[8];
  const float* g1 = (const float*)d_in[9];
  const float* be1 = (const float*)d_in[10];
  const float* wfc1 = (const float*)d_in[11];
  const float* bfc1 = (const float*)d_in[12];
  const float* wfc2 = (const float*)d_in[13];
  const float* bfc2 = (const float*)d_in[14];
  const float* g2 = (const float*)d_in[15];
  const float* be2 = (const float*)d_in[16];

  const long T = 65536;
  char* ws = (char*)d_ws;

  short* WQKVT = (short*)(ws);                 // [1536][512]
  short* WOT = WQKVT + 1536 * 512;             // [512][512]
  short* WFC1T = WOT + 512 * 512;              // [2048][512]
  short* WFC2T = WFC1T + 2048 * 512;           // [512][2048]
  float* BQKV = (float*)(WFC2T + 512 * 2048);  // [1536]
  size_t woff = ((size_t)((char*)(BQKV + 1536) - ws) + 255) & ~(size_t)255;

  size_t avail = (ws_size > woff) ? (ws_size - woff) : 0;
  long Tc = T;
  while (Tc > 256 && (size_t)Tc * 7168 > avail) Tc >>= 1;
  const long nch = T / Tc;

  char* R0 = ws + woff;                // QKV bf16 [Tc][1536] / Y1b bf16 / FF1 bf16 [Tc][2048]
  char* R1 = R0 + (size_t)Tc * 4096;   // XB bf16 (persists through proj)
  char* R1b = R1 + (size_t)Tc * 1024;  // AO bf16 -> Y2b bf16
  char* R2 = R1b + (size_t)Tc * 1024;  // H bf16

  short* QKV = (short*)R0;
  short* Y1b = (short*)R0;
  short* FF1 = (short*)R0;
  short* XB = (short*)R1;
  short* AO = (short*)R1b;
  short* Y2b = (short*)R1b;
  short* H = (short*)R2;

  pack_all<<<3073, 256, 0, stream>>>(wq, wk, wv, wo, wfc1, wfc2, bq, bk, bv,
                                     WQKVT, WOT, WFC1T, WFC2T, BQKV);

  const size_t LDSB = 131072;
  for (long c = 0; c < nch; c++) {
    const long t0 = c * Tc;
    const int mb = (int)(Tc / 256);
    const int mb2 = (int)(Tc / 128);
    cvt_bf16_vec<<<(int)(Tc / 4), 256, 0, stream>>>(x + t0 * 512, XB, Tc * 512);
    gemm256<0><<<mb * 6, 512, LDSB, stream>>>(XB, WQKVT, BQKV, nullptr,
                                              (void*)QKV, 512, 1536, 6);
    attn_win<<<(int)(Tc / 64), 256, 0, stream>>>(QKV, AO);
    gemm256<2><<<mb * 2, 512, LDSB, stream>>>(AO, WOT, bo, XB,
                                              (void*)Y1b, 512, 512, 2);
    ln_rows<1, 1><<<(int)(Tc / 4), 256, 0, stream>>>(nullptr, Y1b, g1, be1, H, nullptr);
    // fc1 + GELU: 128x256 ring (per-wave 64x128, vmcnt(6))
    gemm_bt2<1><<<mb2 * 8, 256, 0, stream>>>(H, WFC1T, bfc1, (void*)FF1, 512, 2048, 8);
    gemm256<2><<<mb * 2, 512, LDSB, stream>>>(FF1, WFC2T, bfc2, H,
                                              (void*)Y2b, 2048, 512, 2);
    ln_rows<1, 0><<<(int)(Tc / 4), 256, 0, stream>>>(nullptr, Y2b, g2, be2, nullptr,
                                                     (float*)d_out + t0 * 512);
  }
}